// Round 7
// baseline (269.496 us; speedup 1.0000x reference)
//
#include <hip/hip_runtime.h>
#include <hip/hip_bf16.h>

#define B_  32
#define S_  1024
#define E_  768
#define HD_ 64
#define M_  (B_*S_)   // 32768 rows of x

typedef __attribute__((ext_vector_type(8))) short short8;   // 8 bf16 (4 VGPR)
typedef __attribute__((ext_vector_type(4))) float float4v;  // MFMA acc

__device__ __forceinline__ float bf2f(unsigned short u) {
    union { unsigned int i; float f; } c; c.i = ((unsigned int)u) << 16; return c.f;
}
// fp32 -> bf16 round-to-nearest-even
__device__ __forceinline__ unsigned short f2bf(float x) {
    union { float f; unsigned u; } c; c.f = x;
    unsigned r = (c.u + 0x7FFFu + ((c.u >> 16) & 1u)) >> 16;
    return (unsigned short)r;
}
// 8 fp32 -> bf16x8 frag
__device__ __forceinline__ short8 load_frag_f32(const float* f) {
    float4 a = *(const float4*)f, b = *(const float4*)(f + 4);
    short8 r;
    r[0] = (short)f2bf(a.x); r[1] = (short)f2bf(a.y);
    r[2] = (short)f2bf(a.z); r[3] = (short)f2bf(a.w);
    r[4] = (short)f2bf(b.x); r[5] = (short)f2bf(b.y);
    r[6] = (short)f2bf(b.z); r[7] = (short)f2bf(b.w);
    return r;
}

// ---------------------------------------------------------------------------
// RoPE tables (blocks 0..127) + dtype sniffer (block 128).
// ---------------------------------------------------------------------------
__global__ __launch_bounds__(256) void setup_kernel(const unsigned int* __restrict__ xw,
                                                    unsigned int* __restrict__ flag,
                                                    float* __restrict__ cs_t,
                                                    float* __restrict__ sn_t) {
    if (blockIdx.x == 128) {   // dtype sniffer (verified rounds 2-6)
        __shared__ int cnt;
        if (threadIdx.x == 0) cnt = 0;
        __syncthreads();
        unsigned int w = xw[(size_t)threadIdx.x * 33331];
        unsigned int e = (w >> 8) & 0x7F;
        int hit = (e >= 0x3B && e <= 0x40) ? 1 : 0;
        atomicAdd(&cnt, hit);
        __syncthreads();
        if (threadIdx.x == 0) *flag = (cnt > 128) ? 1u : 0u;
        return;
    }
    int idx = blockIdx.x * 256 + threadIdx.x;   // 0 .. 32767
    int pos = idx >> 5;
    int ii  = idx & 31;
    float theta = exp2f(-(float)ii * 0.8304820237218406f);  // log2(10000)/16
    float fr = (float)pos * theta;
    float sn, cs;
    sincosf(fr, &sn, &cs);
    cs_t[idx] = cs;
    sn_t[idx] = sn;
}

// ---------------------------------------------------------------------------
// QKV projection + RoPE, MFMA 16x16x32 bf16. BARRIER-FREE, register-pipelined.
// Grid 512, block 256 (4 waves). Block: 64 rows x 192 cols; wave w computes
// 4 m-tiles x 3 n-tiles (ct = w*3+nt). Fragments straight from global:
// A dedups across waves via same-CU L1; W (288 KB) is L2-hot.
// __launch_bounds__(256,3): <=168 VGPR so the 2-deep manual pipeline
// (A/B fragment sets) keeps ~14 loads in flight. No LDS, no __syncthreads.
// ---------------------------------------------------------------------------
__global__ __launch_bounds__(256, 3) void qkv_mfma_kernel(
    const void* __restrict__ x_, const void* __restrict__ Wq_,
    const void* __restrict__ Wk_, const void* __restrict__ Wv_,
    const unsigned int* __restrict__ flag,
    const float* __restrict__ cs_t, const float* __restrict__ sn_t,
    unsigned short* __restrict__ rq, unsigned short* __restrict__ rk,
    unsigned short* __restrict__ vt)
{
    const bool isb = (*flag != 0);
    const int t    = threadIdx.x;
    const int lane = t & 63;
    const int wave = t >> 6;
    const int quad = lane >> 4;
    const int l15  = lane & 15;
    const int row0 = blockIdx.x * 64;

    float4v acc[3][4];
    #pragma unroll
    for (int nt = 0; nt < 3; ++nt)
        #pragma unroll
        for (int mt = 0; mt < 4; ++mt)
            #pragma unroll
            for (int r = 0; r < 4; ++r) acc[nt][mt][r] = 0.f;

    const void* bsrc[3];
    int c0v[3];
    #pragma unroll
    for (int nt = 0; nt < 3; ++nt) {
        int c0 = (wave * 3 + nt) * 16;
        c0v[nt] = c0;
        int region = c0 >> 6;
        bsrc[nt] = (region == 0) ? Wq_ : (region == 1 ? Wk_ : Wv_);
    }

    unsigned aoff[4], boff[3];
    #pragma unroll
    for (int mt = 0; mt < 4; ++mt)
        aoff[mt] = (unsigned)((row0 + mt * 16 + l15) * E_ + quad * 8);
    #pragma unroll
    for (int nt = 0; nt < 3; ++nt)
        boff[nt] = (unsigned)(((c0v[nt] & 63) + l15) * E_ + quad * 8);

    if (isb) {
        const unsigned short* xp = (const unsigned short*)x_;
        auto qload = [&](short8 af[4], short8 bf[3], int kk) {
            #pragma unroll
            for (int mt = 0; mt < 4; ++mt)
                af[mt] = *(const short8*)(xp + aoff[mt] + kk);
            #pragma unroll
            for (int nt = 0; nt < 3; ++nt)
                bf[nt] = *(const short8*)((const unsigned short*)bsrc[nt] + boff[nt] + kk);
        };
        auto qmfma = [&](short8 af[4], short8 bf[3]) {
            #pragma unroll
            for (int nt = 0; nt < 3; ++nt)
                #pragma unroll
                for (int mt = 0; mt < 4; ++mt)
                    acc[nt][mt] = __builtin_amdgcn_mfma_f32_16x16x32_bf16(
                        af[mt], bf[nt], acc[nt][mt], 0, 0, 0);
        };
        short8 afA[4], bfA[3], afB[4], bfB[3];
        qload(afA, bfA, 0);
        #pragma unroll
        for (int kp = 0; kp < 12; ++kp) {        // 12 pairs = 24 k-steps of 32
            qload(afB, bfB, kp * 64 + 32);       // prefetch odd step
            qmfma(afA, bfA);
            if (kp < 11) qload(afA, bfA, kp * 64 + 64);   // prefetch next even
            qmfma(afB, bfB);
        }
    } else {
        // fp32 fallback: correctness-only, unpipelined
        const float* xf = (const float*)x_;
        for (int k0 = 0; k0 < E_; k0 += 32) {
            short8 af[4], bf[3];
            #pragma unroll
            for (int mt = 0; mt < 4; ++mt) af[mt] = load_frag_f32(xf + aoff[mt] + k0);
            #pragma unroll
            for (int nt = 0; nt < 3; ++nt) bf[nt] = load_frag_f32((const float*)bsrc[nt] + boff[nt] + k0);
            #pragma unroll
            for (int nt = 0; nt < 3; ++nt)
                #pragma unroll
                for (int mt = 0; mt < 4; ++mt)
                    acc[nt][mt] = __builtin_amdgcn_mfma_f32_16x16x32_bf16(
                        af[mt], bf[nt], acc[nt][mt], 0, 0, 0);
        }
    }

    // Epilogue (verified rounds 4-6): C col=l15, row=quad*4+r. RoPE q/k; v transposed.
    const int b      = row0 >> 10;
    const int s_in_b = row0 & (S_ - 1);
    #pragma unroll
    for (int nt = 0; nt < 3; ++nt) {
        int c0 = c0v[nt];
        int region = c0 >> 6;          // 0=q, 1=k, 2=v (wave-uniform)
        int d = (c0 & 63) + l15;
        if (region < 2) {
            unsigned short* dst = (region == 0) ? rq : rk;
            int ii = d >> 1;
            #pragma unroll
            for (int mt = 0; mt < 4; ++mt) {
                #pragma unroll
                for (int r = 0; r < 4; ++r) {
                    int row = row0 + mt * 16 + quad * 4 + r;
                    int pos = row & (S_ - 1);
                    float cs = cs_t[pos * 32 + ii];
                    float sn = sn_t[pos * 32 + ii];
                    float val = acc[nt][mt][r];
                    float partner = __shfl_xor(val, 1);   // pair col d^1 = lane^1
                    float res = (d & 1) ? fmaf(val, cs,  partner * sn)
                                        : fmaf(val, cs, -partner * sn);
                    dst[(size_t)row * HD_ + d] = f2bf(res);
                }
            }
        } else {
            #pragma unroll
            for (int mt = 0; mt < 4; ++mt) {
                int sb = s_in_b + mt * 16 + quad * 4;
                ushort4 pk;
                pk.x = f2bf(acc[nt][mt][0]);
                pk.y = f2bf(acc[nt][mt][1]);
                pk.z = f2bf(acc[nt][mt][2]);
                pk.w = f2bf(acc[nt][mt][3]);
                *(ushort4*)(vt + ((size_t)(b * 64 + d) * S_ + sb)) = pk;
            }
        }
    }
}

// ---------------------------------------------------------------------------
// Flash attention, MFMA 16x16x32 bf16, causal. BARRIER-FREE, register-pipelined.
// Grid 512 linear, XCD-swizzled: b = (lin&7)*4 + (lin>>7), qt = (lin>>3)&15
// -> all 16 q-tiles of a batch share one XCD's L2 (KV locality).
// Block 256 (4 waves, 16 q-rows each). KV fragments straight from global
// (L1/L2-resident), 2-deep manual pipeline (A/B sets). P round-trips through
// wave-private LDS (no __syncthreads anywhere).
// __launch_bounds__(256,2): <=256 VGPR for the ~128-VGPR KV pipeline.
// ---------------------------------------------------------------------------
__global__ __launch_bounds__(256, 2) void attn_mfma_kernel(
    const unsigned short* __restrict__ rq, const unsigned short* __restrict__ rk,
    const unsigned short* __restrict__ vt, const unsigned int* __restrict__ flag,
    void* __restrict__ out)
{
    __shared__ unsigned short plds[4][16][72];   // per-wave P buffer

    const bool isb = (*flag != 0);
    const int t    = threadIdx.x;
    const int lane = t & 63;
    const int wave = t >> 6;
    const int quad = lane >> 4;
    const int l15  = lane & 15;
    const int lin  = blockIdx.x + 16 * blockIdx.y;
    const int qt   = (lin >> 3) & 15;
    const int b    = (lin & 7) * 4 + (lin >> 7);
    const int q0   = qt * 64 + wave * 16;
    const float scale = 0.03608439182435161f;   // 768^-0.5

    // Q A-frags (persistent)
    const unsigned short* qp = rq + ((size_t)(b * S_ + q0 + l15)) * HD_ + quad * 8;
    short8 qf0 = *(const short8*)qp;
    short8 qf1 = *(const short8*)(qp + 32);

    const unsigned short* kp = rk + ((size_t)(b * S_ + l15)) * HD_ + quad * 8;
    const unsigned short* vp = vt + ((size_t)(b * 64 + l15)) * S_ + quad * 8;

    float4v o[4];
    float m_[4], l_[4];
    #pragma unroll
    for (int nt = 0; nt < 4; ++nt)
        #pragma unroll
        for (int r = 0; r < 4; ++r) o[nt][r] = 0.f;
    #pragma unroll
    for (int r = 0; r < 4; ++r) { m_[r] = -1e30f; l_[r] = 0.f; }

    auto loadT = [&](int kt, short8 kf[4][2], short8 vf[4][2]) {
        #pragma unroll
        for (int nt = 0; nt < 4; ++nt) {
            const unsigned short* kpp = kp + (size_t)(kt * 64 + nt * 16) * HD_;
            kf[nt][0] = *(const short8*)kpp;
            kf[nt][1] = *(const short8*)(kpp + 32);
            const unsigned short* vpp = vp + (size_t)(nt * 16) * S_ + kt * 64;
            vf[nt][0] = *(const short8*)vpp;
            vf[nt][1] = *(const short8*)(vpp + 32);
        }
    };

    auto compute = [&](int kt, short8 kf[4][2], short8 vf[4][2]) {
        // ---- S = Q K^T ----
        float sc[4][4];
        #pragma unroll
        for (int nt = 0; nt < 4; ++nt) {
            float4v s;
            #pragma unroll
            for (int r = 0; r < 4; ++r) s[r] = 0.f;
            s = __builtin_amdgcn_mfma_f32_16x16x32_bf16(qf0, kf[nt][0], s, 0, 0, 0);
            s = __builtin_amdgcn_mfma_f32_16x16x32_bf16(qf1, kf[nt][1], s, 0, 0, 0);
            #pragma unroll
            for (int r = 0; r < 4; ++r) sc[nt][r] = s[r] * scale;
        }
        if (kt == qt) {   // diagonal: causal mask (block-uniform branch)
            #pragma unroll
            for (int nt = 0; nt < 4; ++nt) {
                int kg = kt * 64 + nt * 16 + l15;
                #pragma unroll
                for (int r = 0; r < 4; ++r) {
                    int qg = q0 + quad * 4 + r;
                    if (kg > qg) sc[nt][r] = -1e30f;
                }
            }
        }
        // ---- online softmax (16-lane reduce) ----
        float mx[4];
        #pragma unroll
        for (int r = 0; r < 4; ++r)
            mx[r] = fmaxf(fmaxf(sc[0][r], sc[1][r]), fmaxf(sc[2][r], sc[3][r]));
        #pragma unroll
        for (int st = 1; st < 16; st <<= 1)
            #pragma unroll
            for (int r = 0; r < 4; ++r)
                mx[r] = fmaxf(mx[r], __shfl_xor(mx[r], st));
        float al[4];
        #pragma unroll
        for (int r = 0; r < 4; ++r) {
            float mn = fmaxf(m_[r], mx[r]);
            al[r] = __expf(m_[r] - mn);
            m_[r] = mn;
        }
        float sm[4] = {0.f, 0.f, 0.f, 0.f};
        #pragma unroll
        for (int nt = 0; nt < 4; ++nt)
            #pragma unroll
            for (int r = 0; r < 4; ++r) {
                float p = __expf(sc[nt][r] - m_[r]);
                sc[nt][r] = p;
                sm[r] += p;
            }
        #pragma unroll
        for (int st = 1; st < 16; st <<= 1)
            #pragma unroll
            for (int r = 0; r < 4; ++r)
                sm[r] += __shfl_xor(sm[r], st);
        #pragma unroll
        for (int r = 0; r < 4; ++r) l_[r] = l_[r] * al[r] + sm[r];
        #pragma unroll
        for (int nt = 0; nt < 4; ++nt)
            #pragma unroll
            for (int r = 0; r < 4; ++r) o[nt][r] *= al[r];
        // ---- P: C-layout -> wave-private LDS -> A-layout ----
        #pragma unroll
        for (int nt = 0; nt < 4; ++nt)
            #pragma unroll
            for (int r = 0; r < 4; ++r)
                plds[wave][quad * 4 + r][nt * 16 + l15] = f2bf(sc[nt][r]);
        short8 pf0 = *(const short8*)&plds[wave][l15][quad * 8];
        short8 pf1 = *(const short8*)&plds[wave][l15][32 + quad * 8];
        // ---- O += P V ----
        #pragma unroll
        for (int nt = 0; nt < 4; ++nt) {
            o[nt] = __builtin_amdgcn_mfma_f32_16x16x32_bf16(pf0, vf[nt][0], o[nt], 0, 0, 0);
            o[nt] = __builtin_amdgcn_mfma_f32_16x16x32_bf16(pf1, vf[nt][1], o[nt], 0, 0, 0);
        }
    };

    short8 kA[4][2], vA[4][2], kB[4][2], vB[4][2];
    loadT(0, kA, vA);
    for (int kt = 0; kt <= qt; kt += 2) {
        loadT(min(kt + 1, qt), kB, vB);     // prefetch (dup tail harmless)
        compute(kt, kA, vA);
        if (kt + 1 > qt) break;
        loadT(min(kt + 2, qt), kA, vA);
        compute(kt + 1, kB, vB);
    }

    // ---- epilogue: normalize, store per dtype ----
    float inv[4];
    #pragma unroll
    for (int r = 0; r < 4; ++r) inv[r] = 1.0f / l_[r];
    if (isb) {
        unsigned short* op = (unsigned short*)out;
        #pragma unroll
        for (int nt = 0; nt < 4; ++nt)
            #pragma unroll
            for (int r = 0; r < 4; ++r) {
                size_t row = (size_t)b * S_ + q0 + quad * 4 + r;
                op[row * HD_ + nt * 16 + l15] = f2bf(o[nt][r] * inv[r]);
            }
    } else {
        float* op = (float*)out;
        #pragma unroll
        for (int nt = 0; nt < 4; ++nt)
            #pragma unroll
            for (int r = 0; r < 4; ++r) {
                size_t row = (size_t)b * S_ + q0 + quad * 4 + r;
                op[row * HD_ + nt * 16 + l15] = o[nt][r] * inv[r];
            }
    }
}

// ---------------------------------------------------------------------------
extern "C" void kernel_launch(void* const* d_in, const int* in_sizes, int n_in,
                              void* d_out, int out_size, void* d_ws, size_t ws_size,
                              hipStream_t stream) {
    const void* x  = d_in[0];
    const void* Wq = d_in[1];
    const void* Wk = d_in[2];
    const void* Wv = d_in[3];

    // ws layout (~12.3 MB; proven available)
    unsigned int* flag = (unsigned int*)d_ws;
    float* cs_t = (float*)d_ws + 64;
    float* sn_t = cs_t + (size_t)S_ * 32;
    unsigned short* rq = (unsigned short*)(sn_t + (size_t)S_ * 32);
    unsigned short* rk = rq + (size_t)M_ * HD_;
    unsigned short* vt = rk + (size_t)M_ * HD_;   // [B][64][S] transposed V

    hipLaunchKernelGGL(setup_kernel, dim3(129), dim3(256), 0, stream,
                       (const unsigned int*)x, flag, cs_t, sn_t);
    hipLaunchKernelGGL(qkv_mfma_kernel, dim3(M_ / 64), dim3(256), 0, stream,
                       x, Wq, Wk, Wv, flag, cs_t, sn_t, rq, rk, vt);
    hipLaunchKernelGGL(attn_mfma_kernel, dim3(S_ / 64, B_), dim3(256), 0, stream,
                       rq, rk, vt, flag, d_out);
}